// Round 2
// baseline (1473.648 us; speedup 1.0000x reference)
//
#include <hip/hip_runtime.h>
#include <hip/hip_bf16.h>
#include <stdint.h>

#define B_ 64
#define T_ 128
#define E_ 256
#define H_ 1024
#define G_ 4096   // 4*H
#define V_ 32000
#define HS_ 65536 // elements per h buffer (64 rows x 1024 cols, bf16)

typedef __attribute__((ext_vector_type(8))) short short8;
typedef __attribute__((ext_vector_type(4))) float floatx4;

static __device__ __forceinline__ unsigned short f2bf(float f){
  union { float f; unsigned u; } v; v.f = f;
  unsigned r = v.u + 0x7FFFu + ((v.u >> 16) & 1u);  // RNE
  return (unsigned short)(r >> 16);
}
static __device__ __forceinline__ float bf2f(unsigned short s){
  union { unsigned u; float f; } v; v.u = ((unsigned)s) << 16;
  return v.f;
}
static __device__ __forceinline__ float sigmoidf_(float x){
  return 1.0f / (1.0f + __expf(-x));
}
static __device__ __forceinline__ float tanhf_(float x){
  const float a = fabsf(x);
  const float t = 1.0f - 2.0f / (__expf(2.0f * a) + 1.0f);
  return __builtin_copysignf(t, x);
}

// ---------------- transpose + bf16-convert the fused LSTM kernel ----------------
__global__ __launch_bounds__(256) void k_transpose(const float* __restrict__ kern,
    unsigned short* __restrict__ wx_t, unsigned short* __restrict__ wh_t){
  __shared__ float tile[32][36];
  const int k0 = blockIdx.x * 32, g0 = blockIdx.y * 32;
  const int r  = threadIdx.x >> 3;
  const int c4 = (threadIdx.x & 7) << 2;
  const float4 v = *reinterpret_cast<const float4*>(kern + (size_t)(k0 + r) * G_ + g0 + c4);
  tile[r][c4 + 0] = v.x; tile[r][c4 + 1] = v.y;
  tile[r][c4 + 2] = v.z; tile[r][c4 + 3] = v.w;
  __syncthreads();
  const unsigned short o0 = f2bf(tile[c4 + 0][r]);
  const unsigned short o1 = f2bf(tile[c4 + 1][r]);
  const unsigned short o2 = f2bf(tile[c4 + 2][r]);
  const unsigned short o3 = f2bf(tile[c4 + 3][r]);
  const ushort4 pk = make_ushort4(o0, o1, o2, o3);
  if (k0 < E_)
    *reinterpret_cast<ushort4*>(wx_t + (size_t)(g0 + r) * E_ + (k0 + c4)) = pk;
  else
    *reinterpret_cast<ushort4*>(wh_t + (size_t)(g0 + r) * H_ + (k0 - E_ + c4)) = pk;
}

// ---------------- xgates, PERMUTED for the LSTM ----------------
// xgp element ((t*256 + wg)*256 + lstm_tid)*4 + reg  (bf16),
// lstm_tid = w*64 + quad*16 + gate*4 + c for gate-col g = gate*1024 + wg*4 + c.
__global__ __launch_bounds__(256) void k_xgates(const float* __restrict__ x,
    const unsigned short* __restrict__ wx_t, const float* __restrict__ bias,
    unsigned short* __restrict__ xgp){
  const int w = threadIdx.x >> 6, l = threadIdx.x & 63;
  const int quad = l >> 4, n = l & 15;
  const int Mbase = blockIdx.x * 64 + w * 16;
  const int Nbase = blockIdx.y * 256;
  const int r = Mbase + n;              // row = t*64 + b
  const int b = r & 63, t = r >> 6;
  const float* arow = x + ((size_t)b * T_ + t) * E_;
  floatx4 acc[16];
  #pragma unroll
  for (int i = 0; i < 16; ++i) acc[i] = (floatx4){0.f,0.f,0.f,0.f};
  #pragma unroll
  for (int kt = 0; kt < 8; ++kt){
    const int k0 = kt * 32 + quad * 8;
    const float4 f0 = *reinterpret_cast<const float4*>(arow + k0);
    const float4 f1 = *reinterpret_cast<const float4*>(arow + k0 + 4);
    short8 af;
    af[0] = (short)f2bf(f0.x); af[1] = (short)f2bf(f0.y);
    af[2] = (short)f2bf(f0.z); af[3] = (short)f2bf(f0.w);
    af[4] = (short)f2bf(f1.x); af[5] = (short)f2bf(f1.y);
    af[6] = (short)f2bf(f1.z); af[7] = (short)f2bf(f1.w);
    const unsigned short* bp = wx_t + (size_t)(Nbase + n) * E_ + k0;
    #pragma unroll
    for (int nt = 0; nt < 16; ++nt){
      const short8 bf = *reinterpret_cast<const short8*>(bp + (size_t)nt * 16 * E_);
      acc[nt] = __builtin_amdgcn_mfma_f32_16x16x32_bf16(af, bf, acc[nt], 0, 0, 0);
    }
  }
  const int t_out = blockIdx.x;
  const int gate = blockIdx.y >> 2;                   // g>>10
  const int np = gate * 4 + (n & 3);                  // gate*4 + c
  #pragma unroll
  for (int nt = 0; nt < 16; ++nt){
    const int g = Nbase + nt * 16 + n;
    const float bi = bias[g];
    const int wgd = (blockIdx.y & 3) * 64 + nt * 4 + (n >> 2);   // (g&1023)>>2
    ushort4 pk;
    pk.x = f2bf(acc[nt][0] + bi);
    pk.y = f2bf(acc[nt][1] + bi);
    pk.z = f2bf(acc[nt][2] + bi);
    pk.w = f2bf(acc[nt][3] + bi);
    *reinterpret_cast<ushort4*>(xgp +
        (((size_t)t_out * 256 + wgd) * 256 + w * 64 + quad * 16 + np) * 4) = pk;
  }
}

// ---------------- persistent LSTM: 256 WGs, 0 LDS ----------------
// Wh slice pinned in AGPRs; h-fragment loads pinned in VGPRs (see R0/R1 notes).
//
// R2 barrier: SPLIT arrival barrier, direct per-wave polling, no master hop.
//  - h cols [0,512) are produced by WGs 0..127 (group A), cols [512,1024) by
//    WGs 128..255 (group B).  The K-reduction consumes A-cols in afr[0..15]
//    and B-cols in afr[16..31], so a consumer only needs group A complete to
//    start the first half of the GEMM.
//  - Arrival: tid0 of each WG adds to its group's line set after stores are
//    drained.  Group A lines: bar[i*32], i=0..15.  Group B: bar[(16+i)*32].
//    8 RMWs/line/step -> negligible serialization.
//  - Wait: EVERY WAVE polls the 16 group lines directly (64 lanes load the
//    same address -> 1 request per line per round), s_sleep(1) backoff.
//    Removes the master-detect + release-store + release-poll chain (~2 RTT)
//    and the second __syncthreads.  The B-poll's first vmcnt also drains the
//    A-half loads, so the A-load RTT hides under it; group-B straggler skew
//    is absorbed before the MFMA block instead of extending a monolithic
//    barrier.
__global__ __launch_bounds__(256, 1) void k_lstm(const unsigned short* __restrict__ wh_t,
    const unsigned short* __restrict__ xgp, unsigned short* __restrict__ hb,
    float* __restrict__ hT, unsigned int* __restrict__ bar){
  const int tid = threadIdx.x;
  const int wg = blockIdx.x;                // owns h-cols [wg*4, wg*4+4)
  const int hbase = wg * 4;
  const int w = tid >> 6, l = tid & 63, quad = l >> 4, n = l & 15;
  const int g_lane = (n >> 2) * H_ + hbase + (n & 3);
  const int rowb = w * 16 + quad * 4;
  const bool low8  = (n & 8) == 0;          // lanes holding (i,j) pairs
  const bool first = (n & 4) == 0;          // first gate of the pair
  const int grp_line = ((wg >> 7) * 16 + (wg & 15)) * 32;  // my arrival line

  short8 bfr[32];
  {
    const unsigned short* bp = wh_t + (size_t)g_lane * H_ + quad * 8;
    #pragma unroll
    for (int kt = 0; kt < 32; ++kt)
      bfr[kt] = *reinterpret_cast<const short8*>(bp + kt * 32);
  }
  #pragma unroll
  for (int kt = 0; kt < 32; ++kt)
    __asm__ volatile("" : "+a"(bfr[kt]));   // park Wh in the AGPR file

  float creg[4] = {0.f, 0.f, 0.f, 0.f};
  ushort4 xgv = *reinterpret_cast<const ushort4*>(xgp + ((size_t)wg * 256 + tid) * 4);

  for (int t = 0; t < T_; ++t){
    const unsigned short* asrc = hb + (size_t)t * HS_ + (size_t)(w * 16 + n) * H_ + quad * 8;
    short8 afr[32];

    // ---- group A: wait, then issue first-half h loads ----
    if (t){
      const unsigned tgt = (unsigned)t * 128u;
      unsigned s;
      for (;;){
        s = 0;
        #pragma unroll
        for (int i = 0; i < 16; ++i)
          s += __hip_atomic_load(&bar[i * 32], __ATOMIC_RELAXED, __HIP_MEMORY_SCOPE_AGENT);
        if (s >= tgt) break;
        __builtin_amdgcn_s_sleep(1);
      }
      __asm__ volatile("" ::: "memory");
    }
    #pragma unroll
    for (int kt = 0; kt < 16; ++kt)
      afr[kt] = *reinterpret_cast<const short8*>(asrc + kt * 32);
    #pragma unroll
    for (int kt = 0; kt < 16; ++kt)
      __asm__ volatile("" : "+v"(afr[kt]));

    // ---- group B: wait (A-load RTT hides under this), then second half ----
    if (t){
      const unsigned tgt = (unsigned)t * 128u;
      unsigned s;
      for (;;){
        s = 0;
        #pragma unroll
        for (int i = 0; i < 16; ++i)
          s += __hip_atomic_load(&bar[(16 + i) * 32], __ATOMIC_RELAXED, __HIP_MEMORY_SCOPE_AGENT);
        if (s >= tgt) break;
        __builtin_amdgcn_s_sleep(1);
      }
      __asm__ volatile("" ::: "memory");
    }
    #pragma unroll
    for (int kt = 16; kt < 32; ++kt)
      afr[kt] = *reinterpret_cast<const short8*>(asrc + kt * 32);
    #pragma unroll
    for (int kt = 16; kt < 32; ++kt)
      __asm__ volatile("" : "+v"(afr[kt]));

    floatx4 a0 = {0.f,0.f,0.f,0.f}, a1 = {0.f,0.f,0.f,0.f};
    floatx4 a2 = {0.f,0.f,0.f,0.f}, a3 = {0.f,0.f,0.f,0.f};
    #pragma unroll
    for (int kt = 0; kt < 32; kt += 4){
      a0 = __builtin_amdgcn_mfma_f32_16x16x32_bf16(afr[kt + 0], bfr[kt + 0], a0, 0, 0, 0);
      a1 = __builtin_amdgcn_mfma_f32_16x16x32_bf16(afr[kt + 1], bfr[kt + 1], a1, 0, 0, 0);
      a2 = __builtin_amdgcn_mfma_f32_16x16x32_bf16(afr[kt + 2], bfr[kt + 2], a2, 0, 0, 0);
      a3 = __builtin_amdgcn_mfma_f32_16x16x32_bf16(afr[kt + 3], bfr[kt + 3], a3, 0, 0, 0);
    }
    floatx4 acc = (a0 + a1) + (a2 + a3);
    acc[0] += bf2f(xgv.x); acc[1] += bf2f(xgv.y);
    acc[2] += bf2f(xgv.z); acc[3] += bf2f(xgv.w);

    // pointwise: lane col n -> gate n>>2, h-offset n&3.  Pair up via shuffles.
    float r1o[4], q1[4], q2[4];
    #pragma unroll
    for (int reg = 0; reg < 4; ++reg){
      const float a_ = acc[reg];
      const float p_ = __shfl_xor(a_, 4);   // swap i<->j and f<->o
      const float x1 = first ? a_ : p_;     // i (low) / f (high)
      const float x2 = first ? p_ : a_;     // j (low) / o (high)
      const float s1 = sigmoidf_(low8 ? x1 : (x1 + 1.0f));   // sig(i) or sig(f+1)
      const float r1 = low8 ? s1 * tanhf_(x2) : s1;          // sig(i)*tanh(j) or sig(f+1)
      const float r2 = low8 ? 0.0f : sigmoidf_(x2);          // sig(o)
      r1o[reg] = r1;
      q1[reg] = __shfl_xor(r1, 8);          // low lanes receive sig(f+1)
      q2[reg] = __shfl_xor(r2, 8);          // low lanes receive sig(o)
    }
    if (n < 4){
      unsigned short* hout = hb + (size_t)(t + 1) * HS_;
      #pragma unroll
      for (int reg = 0; reg < 4; ++reg){
        const float cn = creg[reg] * q1[reg] + r1o[reg];
        creg[reg] = cn;
        const float hv = tanhf_(cn) * q2[reg];
        __hip_atomic_store(&hout[(size_t)(rowb + reg) * H_ + hbase + n], f2bf(hv),
                           __ATOMIC_RELAXED, __HIP_MEMORY_SCOPE_AGENT);
        if (t == T_ - 1) hT[(size_t)(hbase + n) * B_ + rowb + reg] = hv;
      }
    }
    // Arrival: drain stores (syncthreads waits vmcnt0 per wave), then one
    // fire-and-forget add to my group's line.  Waves then run ahead to the
    // next iteration's polls independently -- no second __syncthreads.
    if (t < T_ - 1){
      const ushort4 xgv_n = *reinterpret_cast<const ushort4*>(
          xgp + (((size_t)(t + 1) * 256 + wg) * 256 + tid) * 4);
      __syncthreads();
      if (tid == 0){
        __asm__ volatile("" ::: "memory");
        __hip_atomic_fetch_add(&bar[grp_line], 1u,
                               __ATOMIC_RELAXED, __HIP_MEMORY_SCOPE_AGENT);
      }
      xgv = xgv_n;
    }
  }
}

// ---------------- projection: out = h127 @ w_out + b_out, single pass ----------------
// grid 500, block 256: each block 64 v-cols x 64 b-rows, full K=1024, bias fused.
__global__ __launch_bounds__(256) void k_proj(const float* __restrict__ w_out,
    const float* __restrict__ hT, const float* __restrict__ b_out,
    float* __restrict__ out){
  __shared__ float wsh[32 * 68];
  __shared__ float hsh[32 * 68];
  const int tid = threadIdx.x;
  const int vbase = blockIdx.x * 64;
  const int vq = tid & 15, bg = tid >> 4;
  floatx4 acc[4] = {{0,0,0,0},{0,0,0,0},{0,0,0,0},{0,0,0,0}};
  for (int c = 0; c < 32; ++c){
    const int k0 = c * 32;
    __syncthreads();
    #pragma unroll
    for (int i = 0; i < 2; ++i){
      const int flat = tid + i * 256;
      const int row = flat >> 4, c4 = (flat & 15) << 2;
      *reinterpret_cast<float4*>(&wsh[row * 68 + c4]) =
        *reinterpret_cast<const float4*>(w_out + (size_t)(k0 + row) * V_ + vbase + c4);
      *reinterpret_cast<float4*>(&hsh[row * 68 + c4]) =
        *reinterpret_cast<const float4*>(hT + (size_t)(k0 + row) * B_ + c4);
    }
    __syncthreads();
    #pragma unroll 8
    for (int k = 0; k < 32; ++k){
      const floatx4 wv = *reinterpret_cast<const floatx4*>(&wsh[k * 68 + vq * 4]);
      #pragma unroll
      for (int j = 0; j < 4; ++j){
        acc[j] += hsh[k * 68 + bg * 4 + j] * wv;
      }
    }
  }
  const floatx4 bv = *reinterpret_cast<const floatx4*>(b_out + vbase + vq * 4);
  #pragma unroll
  for (int j = 0; j < 4; ++j){
    *reinterpret_cast<floatx4*>(out + (size_t)(bg * 4 + j) * V_ + vbase + vq * 4) = acc[j] + bv;
  }
}

extern "C" void kernel_launch(void* const* d_in, const int* in_sizes, int n_in,
                              void* d_out, int out_size, void* d_ws, size_t ws_size,
                              hipStream_t stream){
  (void)in_sizes; (void)n_in; (void)out_size; (void)ws_size;
  const float* x     = (const float*)d_in[0];
  const float* kern  = (const float*)d_in[1];
  const float* bias  = (const float*)d_in[2];
  const float* w_out = (const float*)d_in[3];
  const float* b_out = (const float*)d_in[4];
  float* out = (float*)d_out;
  char* ws = (char*)d_ws;

  const size_t BAR_OFF = 0;                              // 4 KB barrier state:
                                                         //  lines 0..15  group A arrivals (128B stride)
                                                         //  lines 16..31 group B arrivals
  const size_t HB_OFF  = 4096;                           // 129 h buffers, bf16 [64][1024]
  const size_t HT_OFF  = HB_OFF + (size_t)129 * 131072;  // h127 transposed fp32 [1024][64]
  const size_t WX_OFF  = HT_OFF + 262144;                // Wx^T bf16 [4096][256]
  const size_t WH_OFF  = WX_OFF + 2097152;               // Wh^T bf16 [4096][1024]
  const size_t XG_OFF  = WH_OFF + 8388608;               // xgates bf16 permuted (67 MB)

  unsigned int*   bar  = (unsigned int*)(ws + BAR_OFF);
  unsigned short* hb   = (unsigned short*)(ws + HB_OFF);
  float*          hT   = (float*)(ws + HT_OFF);
  unsigned short* wx_t = (unsigned short*)(ws + WX_OFF);
  unsigned short* wh_t = (unsigned short*)(ws + WH_OFF);
  unsigned short* xgp  = (unsigned short*)(ws + XG_OFF);

  hipMemsetAsync(ws, 0, HB_OFF + 131072, stream);  // zero barrier + h buffer 0
  k_transpose<<<dim3(40, 128), 256, 0, stream>>>(kern, wx_t, wh_t);
  k_xgates<<<dim3(128, 16), 256, 0, stream>>>(x, wx_t, bias, xgp);
  k_lstm<<<dim3(256), 256, 0, stream>>>(wh_t, xgp, hb, hT, bar);
  k_proj<<<dim3(500), 256, 0, stream>>>(w_out, hT, b_out, out);
}

// Round 3
// 1361.678 us; speedup vs baseline: 1.0822x; 1.0822x over previous
//
#include <hip/hip_runtime.h>
#include <hip/hip_bf16.h>
#include <stdint.h>

#define B_ 64
#define T_ 128
#define E_ 256
#define H_ 1024
#define G_ 4096   // 4*H
#define V_ 32000
#define HS_ 65536 // elements per h buffer (64 rows x 1024 cols, bf16)

typedef __attribute__((ext_vector_type(8))) short short8;
typedef __attribute__((ext_vector_type(4))) float floatx4;

static __device__ __forceinline__ unsigned short f2bf(float f){
  union { float f; unsigned u; } v; v.f = f;
  unsigned r = v.u + 0x7FFFu + ((v.u >> 16) & 1u);  // RNE
  return (unsigned short)(r >> 16);
}
static __device__ __forceinline__ float bf2f(unsigned short s){
  union { unsigned u; float f; } v; v.u = ((unsigned)s) << 16;
  return v.f;
}
static __device__ __forceinline__ float sigmoidf_(float x){
  return 1.0f / (1.0f + __expf(-x));
}
static __device__ __forceinline__ float tanhf_(float x){
  const float a = fabsf(x);
  const float t = 1.0f - 2.0f / (__expf(2.0f * a) + 1.0f);
  return __builtin_copysignf(t, x);
}

// ---------------- transpose + bf16-convert the fused LSTM kernel ----------------
__global__ __launch_bounds__(256) void k_transpose(const float* __restrict__ kern,
    unsigned short* __restrict__ wx_t, unsigned short* __restrict__ wh_t){
  __shared__ float tile[32][36];
  const int k0 = blockIdx.x * 32, g0 = blockIdx.y * 32;
  const int r  = threadIdx.x >> 3;
  const int c4 = (threadIdx.x & 7) << 2;
  const float4 v = *reinterpret_cast<const float4*>(kern + (size_t)(k0 + r) * G_ + g0 + c4);
  tile[r][c4 + 0] = v.x; tile[r][c4 + 1] = v.y;
  tile[r][c4 + 2] = v.z; tile[r][c4 + 3] = v.w;
  __syncthreads();
  const unsigned short o0 = f2bf(tile[c4 + 0][r]);
  const unsigned short o1 = f2bf(tile[c4 + 1][r]);
  const unsigned short o2 = f2bf(tile[c4 + 2][r]);
  const unsigned short o3 = f2bf(tile[c4 + 3][r]);
  const ushort4 pk = make_ushort4(o0, o1, o2, o3);
  if (k0 < E_)
    *reinterpret_cast<ushort4*>(wx_t + (size_t)(g0 + r) * E_ + (k0 + c4)) = pk;
  else
    *reinterpret_cast<ushort4*>(wh_t + (size_t)(g0 + r) * H_ + (k0 - E_ + c4)) = pk;
}

// ---------------- xgates, PERMUTED for the LSTM ----------------
// xgp element ((t*256 + wgd)*256 + lstm_tid)*4 + reg  (bf16),
// lstm_tid = w*64 + quad*16 + gate*4 + c for gate-col g = gate*1024 + wgd*4 + c.
__global__ __launch_bounds__(256) void k_xgates(const float* __restrict__ x,
    const unsigned short* __restrict__ wx_t, const float* __restrict__ bias,
    unsigned short* __restrict__ xgp){
  const int w = threadIdx.x >> 6, l = threadIdx.x & 63;
  const int quad = l >> 4, n = l & 15;
  const int Mbase = blockIdx.x * 64 + w * 16;
  const int Nbase = blockIdx.y * 256;
  const int r = Mbase + n;              // row = t*64 + b
  const int b = r & 63, t = r >> 6;
  const float* arow = x + ((size_t)b * T_ + t) * E_;
  floatx4 acc[16];
  #pragma unroll
  for (int i = 0; i < 16; ++i) acc[i] = (floatx4){0.f,0.f,0.f,0.f};
  #pragma unroll
  for (int kt = 0; kt < 8; ++kt){
    const int k0 = kt * 32 + quad * 8;
    const float4 f0 = *reinterpret_cast<const float4*>(arow + k0);
    const float4 f1 = *reinterpret_cast<const float4*>(arow + k0 + 4);
    short8 af;
    af[0] = (short)f2bf(f0.x); af[1] = (short)f2bf(f0.y);
    af[2] = (short)f2bf(f0.z); af[3] = (short)f2bf(f0.w);
    af[4] = (short)f2bf(f1.x); af[5] = (short)f2bf(f1.y);
    af[6] = (short)f2bf(f1.z); af[7] = (short)f2bf(f1.w);
    const unsigned short* bp = wx_t + (size_t)(Nbase + n) * E_ + k0;
    #pragma unroll
    for (int nt = 0; nt < 16; ++nt){
      const short8 bf = *reinterpret_cast<const short8*>(bp + (size_t)nt * 16 * E_);
      acc[nt] = __builtin_amdgcn_mfma_f32_16x16x32_bf16(af, bf, acc[nt], 0, 0, 0);
    }
  }
  const int t_out = blockIdx.x;
  const int gate = blockIdx.y >> 2;                   // g>>10
  const int np = gate * 4 + (n & 3);                  // gate*4 + c
  #pragma unroll
  for (int nt = 0; nt < 16; ++nt){
    const int g = Nbase + nt * 16 + n;
    const float bi = bias[g];
    const int wgd = (blockIdx.y & 3) * 64 + nt * 4 + (n >> 2);   // (g&1023)>>2
    ushort4 pk;
    pk.x = f2bf(acc[nt][0] + bi);
    pk.y = f2bf(acc[nt][1] + bi);
    pk.z = f2bf(acc[nt][2] + bi);
    pk.w = f2bf(acc[nt][3] + bi);
    *reinterpret_cast<ushort4*>(xgp +
        (((size_t)t_out * 256 + wgd) * 256 + w * 64 + quad * 16 + np) * 4) = pk;
  }
}

// ---------------- persistent LSTM: 128 WGs x 256 threads, k=2 N-tiles/wave ----------------
// R3: halve barrier participants + aggregate h broadcast.  Each WG owns 8
// h-cols (two of the old 4-col slices, s=0,1).  A wave's A-fragment burst is
// SHARED by both N-tiles (same 32x16B loads as R1); Wh doubles to 64 short8
// pinned in AGPRs (256 AGPR + ~200 arch VGPR < 512 unified budget).
// 64 MFMAs/wave/step (~310 cyc, still negligible).
// Barrier: R1's proven master/release structure, 128 arrivals over 16 padded
// lines (8 RMW/line), master (wg0) polls 16 lines, releases 16 lines,
// 127 pollers read-only (<=8/line).  xgv prefetch moved BEFORE the pointwise
// block so its cold-HBM RTT hides under pointwise+stores instead of sitting
// inside the pre-arrival vmcnt drain.
__global__ __launch_bounds__(256, 1) void k_lstm(const unsigned short* __restrict__ wh_t,
    const unsigned short* __restrict__ xgp, unsigned short* __restrict__ hb,
    float* __restrict__ hT, unsigned int* __restrict__ bar){
  const int tid = threadIdx.x;
  const int wg = blockIdx.x;                // owns h-cols [wg*8, wg*8+8)
  const int w = tid >> 6, l = tid & 63, quad = l >> 4, n = l & 15;
  const int rowb = w * 16 + quad * 4;
  const bool low8  = (n & 8) == 0;          // lanes holding (i,j) pairs
  const bool first = (n & 4) == 0;          // first gate of the pair

  // Wh slices for both N-tiles: bfr[0..31] = slice 0, bfr[32..63] = slice 1
  short8 bfr[64];
  #pragma unroll
  for (int s = 0; s < 2; ++s){
    const int g_lane = (n >> 2) * H_ + (2 * wg + s) * 4 + (n & 3);
    const unsigned short* bp = wh_t + (size_t)g_lane * H_ + quad * 8;
    #pragma unroll
    for (int kt = 0; kt < 32; ++kt)
      bfr[s * 32 + kt] = *reinterpret_cast<const short8*>(bp + kt * 32);
  }
  #pragma unroll
  for (int kt = 0; kt < 64; ++kt)
    __asm__ volatile("" : "+a"(bfr[kt]));   // park Wh in the AGPR file

  float creg[2][4] = {{0.f,0.f,0.f,0.f},{0.f,0.f,0.f,0.f}};
  ushort4 xgv0 = *reinterpret_cast<const ushort4*>(xgp + (((size_t)2 * wg + 0) * 256 + tid) * 4);
  ushort4 xgv1 = *reinterpret_cast<const ushort4*>(xgp + (((size_t)2 * wg + 1) * 256 + tid) * 4);

  for (int t = 0; t < T_; ++t){
    // A-fragments: flat burst of 32 x 16B loads of h_t, pinned -> all in flight
    const unsigned short* asrc = hb + (size_t)t * HS_ + (size_t)(w * 16 + n) * H_ + quad * 8;
    short8 afr[32];
    #pragma unroll
    for (int kt = 0; kt < 32; ++kt)
      afr[kt] = *reinterpret_cast<const short8*>(asrc + kt * 32);
    #pragma unroll
    for (int kt = 0; kt < 32; ++kt)
      __asm__ volatile("" : "+v"(afr[kt]));

    floatx4 p0 = {0.f,0.f,0.f,0.f}, p1 = {0.f,0.f,0.f,0.f};
    floatx4 p2 = {0.f,0.f,0.f,0.f}, p3 = {0.f,0.f,0.f,0.f};
    floatx4 q0 = {0.f,0.f,0.f,0.f}, q1_ = {0.f,0.f,0.f,0.f};
    floatx4 q2_ = {0.f,0.f,0.f,0.f}, q3 = {0.f,0.f,0.f,0.f};
    #pragma unroll
    for (int kt = 0; kt < 32; kt += 4){
      p0  = __builtin_amdgcn_mfma_f32_16x16x32_bf16(afr[kt + 0], bfr[kt + 0],      p0, 0, 0, 0);
      q0  = __builtin_amdgcn_mfma_f32_16x16x32_bf16(afr[kt + 0], bfr[32 + kt + 0], q0, 0, 0, 0);
      p1  = __builtin_amdgcn_mfma_f32_16x16x32_bf16(afr[kt + 1], bfr[kt + 1],      p1, 0, 0, 0);
      q1_ = __builtin_amdgcn_mfma_f32_16x16x32_bf16(afr[kt + 1], bfr[32 + kt + 1], q1_, 0, 0, 0);
      p2  = __builtin_amdgcn_mfma_f32_16x16x32_bf16(afr[kt + 2], bfr[kt + 2],      p2, 0, 0, 0);
      q2_ = __builtin_amdgcn_mfma_f32_16x16x32_bf16(afr[kt + 2], bfr[32 + kt + 2], q2_, 0, 0, 0);
      p3  = __builtin_amdgcn_mfma_f32_16x16x32_bf16(afr[kt + 3], bfr[kt + 3],      p3, 0, 0, 0);
      q3  = __builtin_amdgcn_mfma_f32_16x16x32_bf16(afr[kt + 3], bfr[32 + kt + 3], q3, 0, 0, 0);
    }
    floatx4 acc[2];
    acc[0] = (p0 + p1) + (p2 + p3);
    acc[1] = (q0 + q1_) + (q2_ + q3);
    acc[0][0] += bf2f(xgv0.x); acc[0][1] += bf2f(xgv0.y);
    acc[0][2] += bf2f(xgv0.z); acc[0][3] += bf2f(xgv0.w);
    acc[1][0] += bf2f(xgv1.x); acc[1][1] += bf2f(xgv1.y);
    acc[1][2] += bf2f(xgv1.z); acc[1][3] += bf2f(xgv1.w);

    // prefetch next step's x-gates EARLY: RTT hides under pointwise + stores
    ushort4 xgv0n, xgv1n;
    if (t < T_ - 1){
      xgv0n = *reinterpret_cast<const ushort4*>(
          xgp + (((size_t)(t + 1) * 256 + 2 * wg + 0) * 256 + tid) * 4);
      xgv1n = *reinterpret_cast<const ushort4*>(
          xgp + (((size_t)(t + 1) * 256 + 2 * wg + 1) * 256 + tid) * 4);
    }

    // pointwise per slice: lane col n -> gate n>>2, h-offset n&3.
    #pragma unroll
    for (int s = 0; s < 2; ++s){
      float r1o[4], g1[4], g2[4];
      #pragma unroll
      for (int reg = 0; reg < 4; ++reg){
        const float a_ = acc[s][reg];
        const float p_ = __shfl_xor(a_, 4);   // swap i<->j and f<->o
        const float x1 = first ? a_ : p_;     // i (low) / f (high)
        const float x2 = first ? p_ : a_;     // j (low) / o (high)
        const float s1 = sigmoidf_(low8 ? x1 : (x1 + 1.0f));   // sig(i) or sig(f+1)
        const float r1 = low8 ? s1 * tanhf_(x2) : s1;          // sig(i)*tanh(j) or sig(f+1)
        const float r2 = low8 ? 0.0f : sigmoidf_(x2);          // sig(o)
        r1o[reg] = r1;
        g1[reg] = __shfl_xor(r1, 8);          // low lanes receive sig(f+1)
        g2[reg] = __shfl_xor(r2, 8);          // low lanes receive sig(o)
      }
      if (n < 4){
        const int hb_s = (2 * wg + s) * 4;
        unsigned short* hout = hb + (size_t)(t + 1) * HS_;
        #pragma unroll
        for (int reg = 0; reg < 4; ++reg){
          const float cn = creg[s][reg] * g1[reg] + r1o[reg];
          creg[s][reg] = cn;
          const float hv = tanhf_(cn) * g2[reg];
          __hip_atomic_store(&hout[(size_t)(rowb + reg) * H_ + hb_s + n], f2bf(hv),
                             __ATOMIC_RELAXED, __HIP_MEMORY_SCOPE_AGENT);
          if (t == T_ - 1) hT[(size_t)(hb_s + n) * B_ + rowb + reg] = hv;
        }
      }
    }
    // Master/release grid barrier (R1 structure, 128 participants).
    if (t < T_ - 1){
      __syncthreads();                      // drains h stores + xgv prefetch
      if (tid == 0){
        const unsigned step = (unsigned)(t + 1);
        __asm__ volatile("" ::: "memory");
        __hip_atomic_fetch_add(&bar[(wg & 15) * 32], 1u,
                               __ATOMIC_RELAXED, __HIP_MEMORY_SCOPE_AGENT);
        if (wg == 0){
          const unsigned tgt = step * 128u;
          unsigned s;
          do {
            s = 0;
            #pragma unroll
            for (int i = 0; i < 16; ++i)
              s += __hip_atomic_load(&bar[i * 32],
                                     __ATOMIC_RELAXED, __HIP_MEMORY_SCOPE_AGENT);
          } while (s < tgt);
          #pragma unroll
          for (int i = 0; i < 16; ++i)
            __hip_atomic_store(&bar[512 + i * 32], step,
                               __ATOMIC_RELAXED, __HIP_MEMORY_SCOPE_AGENT);
        } else {
          while (__hip_atomic_load(&bar[512 + (wg & 15) * 32],
                                   __ATOMIC_RELAXED, __HIP_MEMORY_SCOPE_AGENT) < step) {}
        }
        __asm__ volatile("" ::: "memory");
      }
      __syncthreads();
      xgv0 = xgv0n; xgv1 = xgv1n;
    }
  }
}

// ---------------- projection: out = h127 @ w_out + b_out, single pass ----------------
// grid 500, block 256: each block 64 v-cols x 64 b-rows, full K=1024, bias fused.
__global__ __launch_bounds__(256) void k_proj(const float* __restrict__ w_out,
    const float* __restrict__ hT, const float* __restrict__ b_out,
    float* __restrict__ out){
  __shared__ float wsh[32 * 68];
  __shared__ float hsh[32 * 68];
  const int tid = threadIdx.x;
  const int vbase = blockIdx.x * 64;
  const int vq = tid & 15, bg = tid >> 4;
  floatx4 acc[4] = {{0,0,0,0},{0,0,0,0},{0,0,0,0},{0,0,0,0}};
  for (int c = 0; c < 32; ++c){
    const int k0 = c * 32;
    __syncthreads();
    #pragma unroll
    for (int i = 0; i < 2; ++i){
      const int flat = tid + i * 256;
      const int row = flat >> 4, c4 = (flat & 15) << 2;
      *reinterpret_cast<float4*>(&wsh[row * 68 + c4]) =
        *reinterpret_cast<const float4*>(w_out + (size_t)(k0 + row) * V_ + vbase + c4);
      *reinterpret_cast<float4*>(&hsh[row * 68 + c4]) =
        *reinterpret_cast<const float4*>(hT + (size_t)(k0 + row) * B_ + c4);
    }
    __syncthreads();
    #pragma unroll 8
    for (int k = 0; k < 32; ++k){
      const floatx4 wv = *reinterpret_cast<const floatx4*>(&wsh[k * 68 + vq * 4]);
      #pragma unroll
      for (int j = 0; j < 4; ++j){
        acc[j] += hsh[k * 68 + bg * 4 + j] * wv;
      }
    }
  }
  const floatx4 bv = *reinterpret_cast<const floatx4*>(b_out + vbase + vq * 4);
  #pragma unroll
  for (int j = 0; j < 4; ++j){
    *reinterpret_cast<floatx4*>(out + (size_t)(bg * 4 + j) * V_ + vbase + vq * 4) = acc[j] + bv;
  }
}

extern "C" void kernel_launch(void* const* d_in, const int* in_sizes, int n_in,
                              void* d_out, int out_size, void* d_ws, size_t ws_size,
                              hipStream_t stream){
  (void)in_sizes; (void)n_in; (void)out_size; (void)ws_size;
  const float* x     = (const float*)d_in[0];
  const float* kern  = (const float*)d_in[1];
  const float* bias  = (const float*)d_in[2];
  const float* w_out = (const float*)d_in[3];
  const float* b_out = (const float*)d_in[4];
  float* out = (float*)d_out;
  char* ws = (char*)d_ws;

  const size_t BAR_OFF = 0;                              // 4 KB barrier state:
                                                         //  [0,2048)   16 arrival lines (128B stride)
                                                         //  [2048,4096) 16 release lines (128B stride)
  const size_t HB_OFF  = 4096;                           // 129 h buffers, bf16 [64][1024]
  const size_t HT_OFF  = HB_OFF + (size_t)129 * 131072;  // h127 transposed fp32 [1024][64]
  const size_t WX_OFF  = HT_OFF + 262144;                // Wx^T bf16 [4096][256]
  const size_t WH_OFF  = WX_OFF + 2097152;               // Wh^T bf16 [4096][1024]
  const size_t XG_OFF  = WH_OFF + 8388608;               // xgates bf16 permuted (67 MB)

  unsigned int*   bar  = (unsigned int*)(ws + BAR_OFF);
  unsigned short* hb   = (unsigned short*)(ws + HB_OFF);
  float*          hT   = (float*)(ws + HT_OFF);
  unsigned short* wx_t = (unsigned short*)(ws + WX_OFF);
  unsigned short* wh_t = (unsigned short*)(ws + WH_OFF);
  unsigned short* xgp  = (unsigned short*)(ws + XG_OFF);

  hipMemsetAsync(ws, 0, HB_OFF + 131072, stream);  // zero barrier + h buffer 0
  k_transpose<<<dim3(40, 128), 256, 0, stream>>>(kern, wx_t, wh_t);
  k_xgates<<<dim3(128, 16), 256, 0, stream>>>(x, wx_t, bias, xgp);
  k_lstm<<<dim3(128), 256, 0, stream>>>(wh_t, xgp, hb, hT, bar);
  k_proj<<<dim3(500), 256, 0, stream>>>(w_out, hT, b_out, out);
}

// Round 4
// 1269.348 us; speedup vs baseline: 1.1609x; 1.0727x over previous
//
#include <hip/hip_runtime.h>
#include <hip/hip_bf16.h>
#include <stdint.h>

#define B_ 64
#define T_ 128
#define E_ 256
#define H_ 1024
#define G_ 4096   // 4*H
#define V_ 32000
#define HS_ 65536 // elements per h buffer (64 rows x 1024 cols, bf16)

typedef __attribute__((ext_vector_type(8))) short short8;
typedef __attribute__((ext_vector_type(4))) float floatx4;
typedef __attribute__((ext_vector_type(4))) unsigned short ushortx4;

static __device__ __forceinline__ unsigned short f2bf(float f){
  union { float f; unsigned u; } v; v.f = f;
  unsigned r = v.u + 0x7FFFu + ((v.u >> 16) & 1u);  // RNE
  return (unsigned short)(r >> 16);
}
static __device__ __forceinline__ float bf2f(unsigned short s){
  union { unsigned u; float f; } v; v.u = ((unsigned)s) << 16;
  return v.f;
}
static __device__ __forceinline__ float sigmoidf_(float x){
  return 1.0f / (1.0f + __expf(-x));
}
static __device__ __forceinline__ float tanhf_(float x){
  const float a = fabsf(x);
  const float t = 1.0f - 2.0f / (__expf(2.0f * a) + 1.0f);
  return __builtin_copysignf(t, x);
}

// ---------------- transpose + bf16-convert the fused LSTM kernel ----------------
__global__ __launch_bounds__(256) void k_transpose(const float* __restrict__ kern,
    unsigned short* __restrict__ wx_t, unsigned short* __restrict__ wh_t){
  __shared__ float tile[32][36];
  const int k0 = blockIdx.x * 32, g0 = blockIdx.y * 32;
  const int r  = threadIdx.x >> 3;
  const int c4 = (threadIdx.x & 7) << 2;
  const float4 v = *reinterpret_cast<const float4*>(kern + (size_t)(k0 + r) * G_ + g0 + c4);
  tile[r][c4 + 0] = v.x; tile[r][c4 + 1] = v.y;
  tile[r][c4 + 2] = v.z; tile[r][c4 + 3] = v.w;
  __syncthreads();
  const unsigned short o0 = f2bf(tile[c4 + 0][r]);
  const unsigned short o1 = f2bf(tile[c4 + 1][r]);
  const unsigned short o2 = f2bf(tile[c4 + 2][r]);
  const unsigned short o3 = f2bf(tile[c4 + 3][r]);
  const ushort4 pk = make_ushort4(o0, o1, o2, o3);
  if (k0 < E_)
    *reinterpret_cast<ushort4*>(wx_t + (size_t)(g0 + r) * E_ + (k0 + c4)) = pk;
  else
    *reinterpret_cast<ushort4*>(wh_t + (size_t)(g0 + r) * H_ + (k0 - E_ + c4)) = pk;
}

// ---------------- xgates, PERMUTED for the LSTM ----------------
// xgp element ((t*256 + wg)*256 + lstm_tid)*4 + reg  (bf16),
// lstm_tid = w*64 + quad*16 + gate*4 + c for gate-col g = gate*1024 + wg*4 + c.
__global__ __launch_bounds__(256) void k_xgates(const float* __restrict__ x,
    const unsigned short* __restrict__ wx_t, const float* __restrict__ bias,
    unsigned short* __restrict__ xgp){
  const int w = threadIdx.x >> 6, l = threadIdx.x & 63;
  const int quad = l >> 4, n = l & 15;
  const int Mbase = blockIdx.x * 64 + w * 16;
  const int Nbase = blockIdx.y * 256;
  const int r = Mbase + n;              // row = t*64 + b
  const int b = r & 63, t = r >> 6;
  const float* arow = x + ((size_t)b * T_ + t) * E_;
  floatx4 acc[16];
  #pragma unroll
  for (int i = 0; i < 16; ++i) acc[i] = (floatx4){0.f,0.f,0.f,0.f};
  #pragma unroll
  for (int kt = 0; kt < 8; ++kt){
    const int k0 = kt * 32 + quad * 8;
    const float4 f0 = *reinterpret_cast<const float4*>(arow + k0);
    const float4 f1 = *reinterpret_cast<const float4*>(arow + k0 + 4);
    short8 af;
    af[0] = (short)f2bf(f0.x); af[1] = (short)f2bf(f0.y);
    af[2] = (short)f2bf(f0.z); af[3] = (short)f2bf(f0.w);
    af[4] = (short)f2bf(f1.x); af[5] = (short)f2bf(f1.y);
    af[6] = (short)f2bf(f1.z); af[7] = (short)f2bf(f1.w);
    const unsigned short* bp = wx_t + (size_t)(Nbase + n) * E_ + k0;
    #pragma unroll
    for (int nt = 0; nt < 16; ++nt){
      const short8 bf = *reinterpret_cast<const short8*>(bp + (size_t)nt * 16 * E_);
      acc[nt] = __builtin_amdgcn_mfma_f32_16x16x32_bf16(af, bf, acc[nt], 0, 0, 0);
    }
  }
  const int t_out = blockIdx.x;
  const int gate = blockIdx.y >> 2;                   // g>>10
  const int np = gate * 4 + (n & 3);                  // gate*4 + c
  #pragma unroll
  for (int nt = 0; nt < 16; ++nt){
    const int g = Nbase + nt * 16 + n;
    const float bi = bias[g];
    const int wgd = (blockIdx.y & 3) * 64 + nt * 4 + (n >> 2);   // (g&1023)>>2
    ushort4 pk;
    pk.x = f2bf(acc[nt][0] + bi);
    pk.y = f2bf(acc[nt][1] + bi);
    pk.z = f2bf(acc[nt][2] + bi);
    pk.w = f2bf(acc[nt][3] + bi);
    *reinterpret_cast<ushort4*>(xgp +
        (((size_t)t_out * 256 + wgd) * 256 + w * 64 + quad * 16 + np) * 4) = pk;
  }
}

// ---------------- persistent LSTM: 256 WGs, 0 LDS (R1 structure) ----------------
// Wh slice pinned in AGPRs; h-fragment loads pinned in VGPRs after a flat
// 32-load burst (R1-proven codegen, VGPR ~148 -- do not perturb the burst).
//
// R4 changes (serial-chain shaving, structure unchanged):
//  1. xgv prefetch hoisted to the TOP of the iteration (issued with the afr
//     burst, pinned): its cold-HBM RTT (~0.4us) hides under MFMA+pointwise
//     instead of sitting inside the pre-arrival vmcnt drain.
//  2. 64 arrival lines (4 RMWs/line) instead of 16 (16/line): cuts LLC
//     atomic serialization of the arrival phase ~4x.
//  3. Wave-parallel master: wave 0 of WG 0 polls all 64 arrival lines with
//     one load per lane per round (+ 6-step shfl_xor reduce), instead of a
//     serial 16-load scalar loop; release = 16 parallel lane stores.
// Layout: arrival lines bar[i*32], i=0..63 (128B stride, 8KB);
//         release lines bar[2048 + j*32], j=0..15.
__global__ __launch_bounds__(256, 1) void k_lstm(const unsigned short* __restrict__ wh_t,
    const unsigned short* __restrict__ xgp, unsigned short* __restrict__ hb,
    float* __restrict__ hT, unsigned int* __restrict__ bar){
  const int tid = threadIdx.x;
  const int wg = blockIdx.x;                // owns h-cols [wg*4, wg*4+4)
  const int hbase = wg * 4;
  const int w = tid >> 6, l = tid & 63, quad = l >> 4, n = l & 15;
  const int g_lane = (n >> 2) * H_ + hbase + (n & 3);
  const int rowb = w * 16 + quad * 4;
  const bool low8  = (n & 8) == 0;          // lanes holding (i,j) pairs
  const bool first = (n & 4) == 0;          // first gate of the pair

  short8 bfr[32];
  {
    const unsigned short* bp = wh_t + (size_t)g_lane * H_ + quad * 8;
    #pragma unroll
    for (int kt = 0; kt < 32; ++kt)
      bfr[kt] = *reinterpret_cast<const short8*>(bp + kt * 32);
  }
  #pragma unroll
  for (int kt = 0; kt < 32; ++kt)
    __asm__ volatile("" : "+a"(bfr[kt]));   // park Wh in the AGPR file

  float creg[4] = {0.f, 0.f, 0.f, 0.f};
  ushortx4 xgv = *reinterpret_cast<const ushortx4*>(xgp + ((size_t)wg * 256 + tid) * 4);

  for (int t = 0; t < T_; ++t){
    // A-fragments: flat burst of 32 x 16B loads of h_t, pinned -> all in flight
    const unsigned short* asrc = hb + (size_t)t * HS_ + (size_t)(w * 16 + n) * H_ + quad * 8;
    short8 afr[32];
    #pragma unroll
    for (int kt = 0; kt < 32; ++kt)
      afr[kt] = *reinterpret_cast<const short8*>(asrc + kt * 32);
    #pragma unroll
    for (int kt = 0; kt < 32; ++kt)
      __asm__ volatile("" : "+v"(afr[kt]));

    // next-step xgates prefetch, issued NOW so the HBM RTT hides under the
    // MFMA + pointwise phases (R4 change 1)
    ushortx4 xgv_n = xgv;
    if (t < T_ - 1){
      xgv_n = *reinterpret_cast<const ushortx4*>(
          xgp + (((size_t)(t + 1) * 256 + wg) * 256 + tid) * 4);
      __asm__ volatile("" : "+v"(xgv_n));
    }

    floatx4 a0 = {0.f,0.f,0.f,0.f}, a1 = {0.f,0.f,0.f,0.f};
    floatx4 a2 = {0.f,0.f,0.f,0.f}, a3 = {0.f,0.f,0.f,0.f};
    #pragma unroll
    for (int kt = 0; kt < 32; kt += 4){
      a0 = __builtin_amdgcn_mfma_f32_16x16x32_bf16(afr[kt + 0], bfr[kt + 0], a0, 0, 0, 0);
      a1 = __builtin_amdgcn_mfma_f32_16x16x32_bf16(afr[kt + 1], bfr[kt + 1], a1, 0, 0, 0);
      a2 = __builtin_amdgcn_mfma_f32_16x16x32_bf16(afr[kt + 2], bfr[kt + 2], a2, 0, 0, 0);
      a3 = __builtin_amdgcn_mfma_f32_16x16x32_bf16(afr[kt + 3], bfr[kt + 3], a3, 0, 0, 0);
    }
    floatx4 acc = (a0 + a1) + (a2 + a3);
    acc[0] += bf2f(xgv[0]); acc[1] += bf2f(xgv[1]);
    acc[2] += bf2f(xgv[2]); acc[3] += bf2f(xgv[3]);

    // pointwise: lane col n -> gate n>>2, h-offset n&3.  Pair up via shuffles.
    float r1o[4], q1[4], q2[4];
    #pragma unroll
    for (int reg = 0; reg < 4; ++reg){
      const float a_ = acc[reg];
      const float p_ = __shfl_xor(a_, 4);   // swap i<->j and f<->o
      const float x1 = first ? a_ : p_;     // i (low) / f (high)
      const float x2 = first ? p_ : a_;     // j (low) / o (high)
      const float s1 = sigmoidf_(low8 ? x1 : (x1 + 1.0f));   // sig(i) or sig(f+1)
      const float r1 = low8 ? s1 * tanhf_(x2) : s1;          // sig(i)*tanh(j) or sig(f+1)
      const float r2 = low8 ? 0.0f : sigmoidf_(x2);          // sig(o)
      r1o[reg] = r1;
      q1[reg] = __shfl_xor(r1, 8);          // low lanes receive sig(f+1)
      q2[reg] = __shfl_xor(r2, 8);          // low lanes receive sig(o)
    }
    if (n < 4){
      unsigned short* hout = hb + (size_t)(t + 1) * HS_;
      #pragma unroll
      for (int reg = 0; reg < 4; ++reg){
        const float cn = creg[reg] * q1[reg] + r1o[reg];
        creg[reg] = cn;
        const float hv = tanhf_(cn) * q2[reg];
        __hip_atomic_store(&hout[(size_t)(rowb + reg) * H_ + hbase + n], f2bf(hv),
                           __ATOMIC_RELAXED, __HIP_MEMORY_SCOPE_AGENT);
        if (t == T_ - 1) hT[(size_t)(hbase + n) * B_ + rowb + reg] = hv;
      }
    }
    // Master/release grid barrier, wave-parallel master (R4 changes 2+3).
    if (t < T_ - 1){
      __syncthreads();                      // drains h stores (vmcnt 0 per wave)
      const unsigned step = (unsigned)(t + 1);
      if (tid == 0){
        __asm__ volatile("" ::: "memory");
        __hip_atomic_fetch_add(&bar[(wg & 63) * 32], 1u,
                               __ATOMIC_RELAXED, __HIP_MEMORY_SCOPE_AGENT);
      }
      if (wg == 0){
        if (tid < 64){
          const unsigned tgt = step * 256u;
          for (;;){
            unsigned s = __hip_atomic_load(&bar[tid * 32],
                                           __ATOMIC_RELAXED, __HIP_MEMORY_SCOPE_AGENT);
            s += __shfl_xor(s, 1);  s += __shfl_xor(s, 2);
            s += __shfl_xor(s, 4);  s += __shfl_xor(s, 8);
            s += __shfl_xor(s, 16); s += __shfl_xor(s, 32);
            if (s >= tgt) break;
          }
          if (tid < 16)
            __hip_atomic_store(&bar[2048 + tid * 32], step,
                               __ATOMIC_RELAXED, __HIP_MEMORY_SCOPE_AGENT);
        }
      } else if (tid == 0){
        while (__hip_atomic_load(&bar[2048 + (wg & 15) * 32],
                                 __ATOMIC_RELAXED, __HIP_MEMORY_SCOPE_AGENT) < step) {}
        __asm__ volatile("" ::: "memory");
      }
      __syncthreads();
      xgv = xgv_n;
    }
  }
}

// ---------------- projection: out = h127 @ w_out + b_out, single pass ----------------
// grid 500, block 256: each block 64 v-cols x 64 b-rows, full K=1024, bias fused.
__global__ __launch_bounds__(256) void k_proj(const float* __restrict__ w_out,
    const float* __restrict__ hT, const float* __restrict__ b_out,
    float* __restrict__ out){
  __shared__ float wsh[32 * 68];
  __shared__ float hsh[32 * 68];
  const int tid = threadIdx.x;
  const int vbase = blockIdx.x * 64;
  const int vq = tid & 15, bg = tid >> 4;
  floatx4 acc[4] = {{0,0,0,0},{0,0,0,0},{0,0,0,0},{0,0,0,0}};
  for (int c = 0; c < 32; ++c){
    const int k0 = c * 32;
    __syncthreads();
    #pragma unroll
    for (int i = 0; i < 2; ++i){
      const int flat = tid + i * 256;
      const int row = flat >> 4, c4 = (flat & 15) << 2;
      *reinterpret_cast<float4*>(&wsh[row * 68 + c4]) =
        *reinterpret_cast<const float4*>(w_out + (size_t)(k0 + row) * V_ + vbase + c4);
      *reinterpret_cast<float4*>(&hsh[row * 68 + c4]) =
        *reinterpret_cast<const float4*>(hT + (size_t)(k0 + row) * B_ + c4);
    }
    __syncthreads();
    #pragma unroll 8
    for (int k = 0; k < 32; ++k){
      const floatx4 wv = *reinterpret_cast<const floatx4*>(&wsh[k * 68 + vq * 4]);
      #pragma unroll
      for (int j = 0; j < 4; ++j){
        acc[j] += hsh[k * 68 + bg * 4 + j] * wv;
      }
    }
  }
  const floatx4 bv = *reinterpret_cast<const floatx4*>(b_out + vbase + vq * 4);
  #pragma unroll
  for (int j = 0; j < 4; ++j){
    *reinterpret_cast<floatx4*>(out + (size_t)(bg * 4 + j) * V_ + vbase + vq * 4) = acc[j] + bv;
  }
}

extern "C" void kernel_launch(void* const* d_in, const int* in_sizes, int n_in,
                              void* d_out, int out_size, void* d_ws, size_t ws_size,
                              hipStream_t stream){
  (void)in_sizes; (void)n_in; (void)out_size; (void)ws_size;
  const float* x     = (const float*)d_in[0];
  const float* kern  = (const float*)d_in[1];
  const float* bias  = (const float*)d_in[2];
  const float* w_out = (const float*)d_in[3];
  const float* b_out = (const float*)d_in[4];
  float* out = (float*)d_out;
  char* ws = (char*)d_ws;

  const size_t BAR_OFF = 0;                              // 16 KB barrier state:
                                                         //  [0,8192)     64 arrival lines (128B stride)
                                                         //  [8192,10240) 16 release lines (128B stride)
  const size_t HB_OFF  = 16384;                          // 129 h buffers, bf16 [64][1024]
  const size_t HT_OFF  = HB_OFF + (size_t)129 * 131072;  // h127 transposed fp32 [1024][64]
  const size_t WX_OFF  = HT_OFF + 262144;                // Wx^T bf16 [4096][256]
  const size_t WH_OFF  = WX_OFF + 2097152;               // Wh^T bf16 [4096][1024]
  const size_t XG_OFF  = WH_OFF + 8388608;               // xgates bf16 permuted (67 MB)

  unsigned int*   bar  = (unsigned int*)(ws + BAR_OFF);
  unsigned short* hb   = (unsigned short*)(ws + HB_OFF);
  float*          hT   = (float*)(ws + HT_OFF);
  unsigned short* wx_t = (unsigned short*)(ws + WX_OFF);
  unsigned short* wh_t = (unsigned short*)(ws + WH_OFF);
  unsigned short* xgp  = (unsigned short*)(ws + XG_OFF);

  hipMemsetAsync(ws, 0, HB_OFF + 131072, stream);  // zero barrier + h buffer 0
  k_transpose<<<dim3(40, 128), 256, 0, stream>>>(kern, wx_t, wh_t);
  k_xgates<<<dim3(128, 16), 256, 0, stream>>>(x, wx_t, bias, xgp);
  k_lstm<<<dim3(256), 256, 0, stream>>>(wh_t, xgp, hb, hT, bar);
  k_proj<<<dim3(500), 256, 0, stream>>>(w_out, hT, b_out, out);
}

// Round 5
// 1248.411 us; speedup vs baseline: 1.1804x; 1.0168x over previous
//
#include <hip/hip_runtime.h>
#include <hip/hip_bf16.h>
#include <stdint.h>

#define B_ 64
#define T_ 128
#define E_ 256
#define H_ 1024
#define G_ 4096   // 4*H
#define V_ 32000
#define HS_ 65536 // elements per h buffer (64 rows x 1024 cols, bf16)

typedef __attribute__((ext_vector_type(8))) short short8;
typedef __attribute__((ext_vector_type(4))) float floatx4;
typedef __attribute__((ext_vector_type(4))) unsigned short ushortx4;

static __device__ __forceinline__ unsigned short f2bf(float f){
  union { float f; unsigned u; } v; v.f = f;
  unsigned r = v.u + 0x7FFFu + ((v.u >> 16) & 1u);  // RNE
  return (unsigned short)(r >> 16);
}
static __device__ __forceinline__ float bf2f(unsigned short s){
  union { unsigned u; float f; } v; v.u = ((unsigned)s) << 16;
  return v.f;
}
static __device__ __forceinline__ float sigmoidf_(float x){
  return 1.0f / (1.0f + __expf(-x));
}
static __device__ __forceinline__ float tanhf_(float x){
  const float a = fabsf(x);
  const float t = 1.0f - 2.0f / (__expf(2.0f * a) + 1.0f);
  return __builtin_copysignf(t, x);
}

// ---------------- transpose + bf16-convert the fused LSTM kernel ----------------
__global__ __launch_bounds__(256) void k_transpose(const float* __restrict__ kern,
    unsigned short* __restrict__ wx_t, unsigned short* __restrict__ wh_t){
  __shared__ float tile[32][36];
  const int k0 = blockIdx.x * 32, g0 = blockIdx.y * 32;
  const int r  = threadIdx.x >> 3;
  const int c4 = (threadIdx.x & 7) << 2;
  const float4 v = *reinterpret_cast<const float4*>(kern + (size_t)(k0 + r) * G_ + g0 + c4);
  tile[r][c4 + 0] = v.x; tile[r][c4 + 1] = v.y;
  tile[r][c4 + 2] = v.z; tile[r][c4 + 3] = v.w;
  __syncthreads();
  const unsigned short o0 = f2bf(tile[c4 + 0][r]);
  const unsigned short o1 = f2bf(tile[c4 + 1][r]);
  const unsigned short o2 = f2bf(tile[c4 + 2][r]);
  const unsigned short o3 = f2bf(tile[c4 + 3][r]);
  const ushort4 pk = make_ushort4(o0, o1, o2, o3);
  if (k0 < E_)
    *reinterpret_cast<ushort4*>(wx_t + (size_t)(g0 + r) * E_ + (k0 + c4)) = pk;
  else
    *reinterpret_cast<ushort4*>(wh_t + (size_t)(g0 + r) * H_ + (k0 - E_ + c4)) = pk;
}

// ---------------- xgates, PERMUTED for the LSTM ----------------
// xgp element ((t*256 + wg)*256 + lstm_tid)*4 + reg  (bf16),
// lstm_tid = w*64 + quad*16 + gate*4 + c for gate-col g = gate*1024 + wg*4 + c.
__global__ __launch_bounds__(256) void k_xgates(const float* __restrict__ x,
    const unsigned short* __restrict__ wx_t, const float* __restrict__ bias,
    unsigned short* __restrict__ xgp){
  const int w = threadIdx.x >> 6, l = threadIdx.x & 63;
  const int quad = l >> 4, n = l & 15;
  const int Mbase = blockIdx.x * 64 + w * 16;
  const int Nbase = blockIdx.y * 256;
  const int r = Mbase + n;              // row = t*64 + b
  const int b = r & 63, t = r >> 6;
  const float* arow = x + ((size_t)b * T_ + t) * E_;
  floatx4 acc[16];
  #pragma unroll
  for (int i = 0; i < 16; ++i) acc[i] = (floatx4){0.f,0.f,0.f,0.f};
  #pragma unroll
  for (int kt = 0; kt < 8; ++kt){
    const int k0 = kt * 32 + quad * 8;
    const float4 f0 = *reinterpret_cast<const float4*>(arow + k0);
    const float4 f1 = *reinterpret_cast<const float4*>(arow + k0 + 4);
    short8 af;
    af[0] = (short)f2bf(f0.x); af[1] = (short)f2bf(f0.y);
    af[2] = (short)f2bf(f0.z); af[3] = (short)f2bf(f0.w);
    af[4] = (short)f2bf(f1.x); af[5] = (short)f2bf(f1.y);
    af[6] = (short)f2bf(f1.z); af[7] = (short)f2bf(f1.w);
    const unsigned short* bp = wx_t + (size_t)(Nbase + n) * E_ + k0;
    #pragma unroll
    for (int nt = 0; nt < 16; ++nt){
      const short8 bf = *reinterpret_cast<const short8*>(bp + (size_t)nt * 16 * E_);
      acc[nt] = __builtin_amdgcn_mfma_f32_16x16x32_bf16(af, bf, acc[nt], 0, 0, 0);
    }
  }
  const int t_out = blockIdx.x;
  const int gate = blockIdx.y >> 2;                   // g>>10
  const int np = gate * 4 + (n & 3);                  // gate*4 + c
  #pragma unroll
  for (int nt = 0; nt < 16; ++nt){
    const int g = Nbase + nt * 16 + n;
    const float bi = bias[g];
    const int wgd = (blockIdx.y & 3) * 64 + nt * 4 + (n >> 2);   // (g&1023)>>2
    ushort4 pk;
    pk.x = f2bf(acc[nt][0] + bi);
    pk.y = f2bf(acc[nt][1] + bi);
    pk.z = f2bf(acc[nt][2] + bi);
    pk.w = f2bf(acc[nt][3] + bi);
    *reinterpret_cast<ushort4*>(xgp +
        (((size_t)t_out * 256 + wgd) * 256 + w * 64 + quad * 16 + np) * 4) = pk;
  }
}

// ---------------- persistent LSTM: 256 WGs, 0 LDS (R1 structure) ----------------
// Wh slice pinned in AGPRs; h-fragment loads pinned in VGPRs after a flat
// 32-load burst (R1-proven codegen -- compute path untouched this round).
//
// R5 changes (each argued against vmcnt semantics; release path unchanged):
//  (a) FLAG arrival, no RMW: tid0 stores the step number to flags[wg]
//      (bar[wg], 16 flags/64B line).  R0->R1 showed same-line RMWs serialize
//      at ~30-90ns each (16/line = 0.3-0.6us); single-writer plain stores
//      just post and merge.
//  (b) Wave-parallel master detect: wave 0 of WG 0 loads all 256 flags
//      (4 agent-loads/lane, one parallel LLC round) + 6-step shfl_xor
//      min-reduce, loops until min >= step.  Replaces serial-16 poll rounds.
//  (c) Own-step xgv load at iteration top, issued AFTER the 32 afr loads and
//      BEFORE the pins: afr pins wait at vmcnt(1) (xgv youngest in flight),
//      xgv's own wait lands after the MFMA block -> its ~900cyc cold-HBM RTT
//      hides under afr-wait + MFMA instead of sitting in the pre-barrier
//      vmcnt(0) drain (R1) or blocking MFMA issue (R4's pin mistake).
// Layout: flags bar[0..255] (1KB); release lines bar[512 + j*32], j=0..15.
__global__ __launch_bounds__(256, 1) void k_lstm(const unsigned short* __restrict__ wh_t,
    const unsigned short* __restrict__ xgp, unsigned short* __restrict__ hb,
    float* __restrict__ hT, unsigned int* __restrict__ bar){
  const int tid = threadIdx.x;
  const int wg = blockIdx.x;                // owns h-cols [wg*4, wg*4+4)
  const int hbase = wg * 4;
  const int w = tid >> 6, l = tid & 63, quad = l >> 4, n = l & 15;
  const int g_lane = (n >> 2) * H_ + hbase + (n & 3);
  const int rowb = w * 16 + quad * 4;
  const bool low8  = (n & 8) == 0;          // lanes holding (i,j) pairs
  const bool first = (n & 4) == 0;          // first gate of the pair

  short8 bfr[32];
  {
    const unsigned short* bp = wh_t + (size_t)g_lane * H_ + quad * 8;
    #pragma unroll
    for (int kt = 0; kt < 32; ++kt)
      bfr[kt] = *reinterpret_cast<const short8*>(bp + kt * 32);
  }
  #pragma unroll
  for (int kt = 0; kt < 32; ++kt)
    __asm__ volatile("" : "+a"(bfr[kt]));   // park Wh in the AGPR file

  float creg[4] = {0.f, 0.f, 0.f, 0.f};

  for (int t = 0; t < T_; ++t){
    // A-fragments: flat burst of 32 x 16B loads of h_t, pinned -> all in flight
    const unsigned short* asrc = hb + (size_t)t * HS_ + (size_t)(w * 16 + n) * H_ + quad * 8;
    short8 afr[32];
    #pragma unroll
    for (int kt = 0; kt < 32; ++kt)
      afr[kt] = *reinterpret_cast<const short8*>(asrc + kt * 32);
    // own-step x-gates load: youngest outstanding VMEM op, so the afr pins
    // below wait at vmcnt(1) and this load's RTT hides under afr-wait + MFMA
    const ushortx4 xgv = *reinterpret_cast<const ushortx4*>(
        xgp + (((size_t)t * 256 + wg) * 256 + tid) * 4);
    #pragma unroll
    for (int kt = 0; kt < 32; ++kt)
      __asm__ volatile("" : "+v"(afr[kt]));

    floatx4 a0 = {0.f,0.f,0.f,0.f}, a1 = {0.f,0.f,0.f,0.f};
    floatx4 a2 = {0.f,0.f,0.f,0.f}, a3 = {0.f,0.f,0.f,0.f};
    #pragma unroll
    for (int kt = 0; kt < 32; kt += 4){
      a0 = __builtin_amdgcn_mfma_f32_16x16x32_bf16(afr[kt + 0], bfr[kt + 0], a0, 0, 0, 0);
      a1 = __builtin_amdgcn_mfma_f32_16x16x32_bf16(afr[kt + 1], bfr[kt + 1], a1, 0, 0, 0);
      a2 = __builtin_amdgcn_mfma_f32_16x16x32_bf16(afr[kt + 2], bfr[kt + 2], a2, 0, 0, 0);
      a3 = __builtin_amdgcn_mfma_f32_16x16x32_bf16(afr[kt + 3], bfr[kt + 3], a3, 0, 0, 0);
    }
    floatx4 acc = (a0 + a1) + (a2 + a3);
    acc[0] += bf2f(xgv[0]); acc[1] += bf2f(xgv[1]);
    acc[2] += bf2f(xgv[2]); acc[3] += bf2f(xgv[3]);

    // pointwise: lane col n -> gate n>>2, h-offset n&3.  Pair up via shuffles.
    float r1o[4], q1[4], q2[4];
    #pragma unroll
    for (int reg = 0; reg < 4; ++reg){
      const float a_ = acc[reg];
      const float p_ = __shfl_xor(a_, 4);   // swap i<->j and f<->o
      const float x1 = first ? a_ : p_;     // i (low) / f (high)
      const float x2 = first ? p_ : a_;     // j (low) / o (high)
      const float s1 = sigmoidf_(low8 ? x1 : (x1 + 1.0f));   // sig(i) or sig(f+1)
      const float r1 = low8 ? s1 * tanhf_(x2) : s1;          // sig(i)*tanh(j) or sig(f+1)
      const float r2 = low8 ? 0.0f : sigmoidf_(x2);          // sig(o)
      r1o[reg] = r1;
      q1[reg] = __shfl_xor(r1, 8);          // low lanes receive sig(f+1)
      q2[reg] = __shfl_xor(r2, 8);          // low lanes receive sig(o)
    }
    if (n < 4){
      unsigned short* hout = hb + (size_t)(t + 1) * HS_;
      #pragma unroll
      for (int reg = 0; reg < 4; ++reg){
        const float cn = creg[reg] * q1[reg] + r1o[reg];
        creg[reg] = cn;
        const float hv = tanhf_(cn) * q2[reg];
        __hip_atomic_store(&hout[(size_t)(rowb + reg) * H_ + hbase + n], f2bf(hv),
                           __ATOMIC_RELAXED, __HIP_MEMORY_SCOPE_AGENT);
        if (t == T_ - 1) hT[(size_t)(hbase + n) * B_ + rowb + reg] = hv;
      }
    }
    // Flag-arrival + wave-parallel-master + release barrier (R5 changes a+b).
    if (t < T_ - 1){
      __syncthreads();                      // drains h stores (vmcnt 0 per wave)
      const unsigned step = (unsigned)(t + 1);
      if (tid == 0){
        __asm__ volatile("" ::: "memory");
        __hip_atomic_store(&bar[wg], step,
                           __ATOMIC_RELAXED, __HIP_MEMORY_SCOPE_AGENT);
      }
      if (wg == 0){
        if (tid < 64){
          for (;;){
            const unsigned f0 = __hip_atomic_load(&bar[tid * 4 + 0],
                                  __ATOMIC_RELAXED, __HIP_MEMORY_SCOPE_AGENT);
            const unsigned f1 = __hip_atomic_load(&bar[tid * 4 + 1],
                                  __ATOMIC_RELAXED, __HIP_MEMORY_SCOPE_AGENT);
            const unsigned f2 = __hip_atomic_load(&bar[tid * 4 + 2],
                                  __ATOMIC_RELAXED, __HIP_MEMORY_SCOPE_AGENT);
            const unsigned f3 = __hip_atomic_load(&bar[tid * 4 + 3],
                                  __ATOMIC_RELAXED, __HIP_MEMORY_SCOPE_AGENT);
            unsigned m = min(min(f0, f1), min(f2, f3));
            m = min(m, (unsigned)__shfl_xor((int)m, 1));
            m = min(m, (unsigned)__shfl_xor((int)m, 2));
            m = min(m, (unsigned)__shfl_xor((int)m, 4));
            m = min(m, (unsigned)__shfl_xor((int)m, 8));
            m = min(m, (unsigned)__shfl_xor((int)m, 16));
            m = min(m, (unsigned)__shfl_xor((int)m, 32));
            if (m >= step) break;
          }
          if (tid < 16)
            __hip_atomic_store(&bar[512 + tid * 32], step,
                               __ATOMIC_RELAXED, __HIP_MEMORY_SCOPE_AGENT);
        }
      } else if (tid == 0){
        while (__hip_atomic_load(&bar[512 + (wg & 15) * 32],
                                 __ATOMIC_RELAXED, __HIP_MEMORY_SCOPE_AGENT) < step) {}
        __asm__ volatile("" ::: "memory");
      }
      __syncthreads();
    }
  }
}

// ---------------- projection: out = h127 @ w_out + b_out, single pass ----------------
// grid 500, block 256: each block 64 v-cols x 64 b-rows, full K=1024, bias fused.
__global__ __launch_bounds__(256) void k_proj(const float* __restrict__ w_out,
    const float* __restrict__ hT, const float* __restrict__ b_out,
    float* __restrict__ out){
  __shared__ float wsh[32 * 68];
  __shared__ float hsh[32 * 68];
  const int tid = threadIdx.x;
  const int vbase = blockIdx.x * 64;
  const int vq = tid & 15, bg = tid >> 4;
  floatx4 acc[4] = {{0,0,0,0},{0,0,0,0},{0,0,0,0},{0,0,0,0}};
  for (int c = 0; c < 32; ++c){
    const int k0 = c * 32;
    __syncthreads();
    #pragma unroll
    for (int i = 0; i < 2; ++i){
      const int flat = tid + i * 256;
      const int row = flat >> 4, c4 = (flat & 15) << 2;
      *reinterpret_cast<float4*>(&wsh[row * 68 + c4]) =
        *reinterpret_cast<const float4*>(w_out + (size_t)(k0 + row) * V_ + vbase + c4);
      *reinterpret_cast<float4*>(&hsh[row * 68 + c4]) =
        *reinterpret_cast<const float4*>(hT + (size_t)(k0 + row) * B_ + c4);
    }
    __syncthreads();
    #pragma unroll 8
    for (int k = 0; k < 32; ++k){
      const floatx4 wv = *reinterpret_cast<const floatx4*>(&wsh[k * 68 + vq * 4]);
      #pragma unroll
      for (int j = 0; j < 4; ++j){
        acc[j] += hsh[k * 68 + bg * 4 + j] * wv;
      }
    }
  }
  const floatx4 bv = *reinterpret_cast<const floatx4*>(b_out + vbase + vq * 4);
  #pragma unroll
  for (int j = 0; j < 4; ++j){
    *reinterpret_cast<floatx4*>(out + (size_t)(bg * 4 + j) * V_ + vbase + vq * 4) = acc[j] + bv;
  }
}

extern "C" void kernel_launch(void* const* d_in, const int* in_sizes, int n_in,
                              void* d_out, int out_size, void* d_ws, size_t ws_size,
                              hipStream_t stream){
  (void)in_sizes; (void)n_in; (void)out_size; (void)ws_size;
  const float* x     = (const float*)d_in[0];
  const float* kern  = (const float*)d_in[1];
  const float* bias  = (const float*)d_in[2];
  const float* w_out = (const float*)d_in[3];
  const float* b_out = (const float*)d_in[4];
  float* out = (float*)d_out;
  char* ws = (char*)d_ws;

  const size_t BAR_OFF = 0;                              // 4 KB barrier state:
                                                         //  [0,1024)    256 arrival flags (4B each)
                                                         //  [2048,4096) 16 release lines (128B stride)
  const size_t HB_OFF  = 4096;                           // 129 h buffers, bf16 [64][1024]
  const size_t HT_OFF  = HB_OFF + (size_t)129 * 131072;  // h127 transposed fp32 [1024][64]
  const size_t WX_OFF  = HT_OFF + 262144;                // Wx^T bf16 [4096][256]
  const size_t WH_OFF  = WX_OFF + 2097152;               // Wh^T bf16 [4096][1024]
  const size_t XG_OFF  = WH_OFF + 8388608;               // xgates bf16 permuted (67 MB)

  unsigned int*   bar  = (unsigned int*)(ws + BAR_OFF);
  unsigned short* hb   = (unsigned short*)(ws + HB_OFF);
  float*          hT   = (float*)(ws + HT_OFF);
  unsigned short* wx_t = (unsigned short*)(ws + WX_OFF);
  unsigned short* wh_t = (unsigned short*)(ws + WH_OFF);
  unsigned short* xgp  = (unsigned short*)(ws + XG_OFF);

  hipMemsetAsync(ws, 0, HB_OFF + 131072, stream);  // zero barrier + h buffer 0
  k_transpose<<<dim3(40, 128), 256, 0, stream>>>(kern, wx_t, wh_t);
  k_xgates<<<dim3(128, 16), 256, 0, stream>>>(x, wx_t, bias, xgp);
  k_lstm<<<dim3(256), 256, 0, stream>>>(wh_t, xgp, hb, hT, bar);
  k_proj<<<dim3(500), 256, 0, stream>>>(w_out, hT, b_out, out);
}

// Round 6
// 1208.332 us; speedup vs baseline: 1.2196x; 1.0332x over previous
//
#include <hip/hip_runtime.h>
#include <hip/hip_bf16.h>
#include <stdint.h>

#define B_ 64
#define T_ 128
#define E_ 256
#define H_ 1024
#define G_ 4096   // 4*H
#define V_ 32000
#define HS_ 65536 // elements per h buffer (64 rows x 1024 cols, bf16)

typedef __attribute__((ext_vector_type(8))) short short8;
typedef __attribute__((ext_vector_type(4))) float floatx4;

static __device__ __forceinline__ unsigned short f2bf(float f){
  union { float f; unsigned u; } v; v.f = f;
  unsigned r = v.u + 0x7FFFu + ((v.u >> 16) & 1u);  // RNE
  return (unsigned short)(r >> 16);
}
static __device__ __forceinline__ float bf2f(unsigned short s){
  union { unsigned u; float f; } v; v.u = ((unsigned)s) << 16;
  return v.f;
}
static __device__ __forceinline__ float sigmoidf_(float x){
  return 1.0f / (1.0f + __expf(-x));
}
static __device__ __forceinline__ float tanhf_(float x){
  const float a = fabsf(x);
  const float t = 1.0f - 2.0f / (__expf(2.0f * a) + 1.0f);
  return __builtin_copysignf(t, x);
}

// ---------------- transpose + bf16-convert the fused LSTM kernel ----------------
__global__ __launch_bounds__(256) void k_transpose(const float* __restrict__ kern,
    unsigned short* __restrict__ wx_t, unsigned short* __restrict__ wh_t){
  __shared__ float tile[32][36];
  const int k0 = blockIdx.x * 32, g0 = blockIdx.y * 32;
  const int r  = threadIdx.x >> 3;
  const int c4 = (threadIdx.x & 7) << 2;
  const float4 v = *reinterpret_cast<const float4*>(kern + (size_t)(k0 + r) * G_ + g0 + c4);
  tile[r][c4 + 0] = v.x; tile[r][c4 + 1] = v.y;
  tile[r][c4 + 2] = v.z; tile[r][c4 + 3] = v.w;
  __syncthreads();
  const unsigned short o0 = f2bf(tile[c4 + 0][r]);
  const unsigned short o1 = f2bf(tile[c4 + 1][r]);
  const unsigned short o2 = f2bf(tile[c4 + 2][r]);
  const unsigned short o3 = f2bf(tile[c4 + 3][r]);
  const ushort4 pk = make_ushort4(o0, o1, o2, o3);
  if (k0 < E_)
    *reinterpret_cast<ushort4*>(wx_t + (size_t)(g0 + r) * E_ + (k0 + c4)) = pk;
  else
    *reinterpret_cast<ushort4*>(wh_t + (size_t)(g0 + r) * H_ + (k0 - E_ + c4)) = pk;
}

// ---------------- xgates, PERMUTED for the LSTM ----------------
// xgp element ((t*256 + wg)*256 + lstm_tid)*4 + reg  (bf16),
// lstm_tid = w*64 + quad*16 + gate*4 + c for gate-col g = gate*1024 + wg*4 + c.
__global__ __launch_bounds__(256) void k_xgates(const float* __restrict__ x,
    const unsigned short* __restrict__ wx_t, const float* __restrict__ bias,
    unsigned short* __restrict__ xgp){
  const int w = threadIdx.x >> 6, l = threadIdx.x & 63;
  const int quad = l >> 4, n = l & 15;
  const int Mbase = blockIdx.x * 64 + w * 16;
  const int Nbase = blockIdx.y * 256;
  const int r = Mbase + n;              // row = t*64 + b
  const int b = r & 63, t = r >> 6;
  const float* arow = x + ((size_t)b * T_ + t) * E_;
  floatx4 acc[16];
  #pragma unroll
  for (int i = 0; i < 16; ++i) acc[i] = (floatx4){0.f,0.f,0.f,0.f};
  #pragma unroll
  for (int kt = 0; kt < 8; ++kt){
    const int k0 = kt * 32 + quad * 8;
    const float4 f0 = *reinterpret_cast<const float4*>(arow + k0);
    const float4 f1 = *reinterpret_cast<const float4*>(arow + k0 + 4);
    short8 af;
    af[0] = (short)f2bf(f0.x); af[1] = (short)f2bf(f0.y);
    af[2] = (short)f2bf(f0.z); af[3] = (short)f2bf(f0.w);
    af[4] = (short)f2bf(f1.x); af[5] = (short)f2bf(f1.y);
    af[6] = (short)f2bf(f1.z); af[7] = (short)f2bf(f1.w);
    const unsigned short* bp = wx_t + (size_t)(Nbase + n) * E_ + k0;
    #pragma unroll
    for (int nt = 0; nt < 16; ++nt){
      const short8 bf = *reinterpret_cast<const short8*>(bp + (size_t)nt * 16 * E_);
      acc[nt] = __builtin_amdgcn_mfma_f32_16x16x32_bf16(af, bf, acc[nt], 0, 0, 0);
    }
  }
  const int t_out = blockIdx.x;
  const int gate = blockIdx.y >> 2;                   // g>>10
  const int np = gate * 4 + (n & 3);                  // gate*4 + c
  #pragma unroll
  for (int nt = 0; nt < 16; ++nt){
    const int g = Nbase + nt * 16 + n;
    const float bi = bias[g];
    const int wgd = (blockIdx.y & 3) * 64 + nt * 4 + (n >> 2);   // (g&1023)>>2
    ushort4 pk;
    pk.x = f2bf(acc[nt][0] + bi);
    pk.y = f2bf(acc[nt][1] + bi);
    pk.z = f2bf(acc[nt][2] + bi);
    pk.w = f2bf(acc[nt][3] + bi);
    *reinterpret_cast<ushort4*>(xgp +
        (((size_t)t_out * 256 + wgd) * 256 + w * 64 + quad * 16 + np) * 4) = pk;
  }
}

// ---------------- persistent LSTM: 256 WGs, 0 LDS (R1 structure, verbatim) ----------------
// Wh slice pinned in AGPRs; h-fragment loads pinned in VGPRs after a flat
// 32-load burst -> single s_waitcnt, one L3 round-trip per step.
// Barrier: R1's proven two-phase master/release (fetch_add arrival on 16
// padded lines; master wg0/tid0 polls 16 lines -- the compiler batches the 16
// independent atomic loads before one waitcnt, so a poll round is already
// ~1 LLC RTT; release to 16 padded lines; 255 tid0 pollers).
//
// R6: ONE change -- software-pipelined polling to cut detect QUANTIZATION
// (detection happens up to a full poll period after the state flips):
//  - master keeps TWO independent 16-load batches in flight (checks batch A
//    while batch B is already issued) -> detect granularity RTT/2;
//  - release pollers issue 4 sequential loads of their line per round and
//    check incrementally -> granularity RTT/4 (read-only lines, 16 pollers
//    each, ~4x traffic is well within LLC same-address service rate).
// Everything else byte-identical to R1; VGPR_Count=148 is the canary.
__global__ __launch_bounds__(256, 1) void k_lstm(const unsigned short* __restrict__ wh_t,
    const unsigned short* __restrict__ xgp, unsigned short* __restrict__ hb,
    float* __restrict__ hT, unsigned int* __restrict__ bar){
  const int tid = threadIdx.x;
  const int wg = blockIdx.x;                // owns h-cols [wg*4, wg*4+4)
  const int hbase = wg * 4;
  const int w = tid >> 6, l = tid & 63, quad = l >> 4, n = l & 15;
  const int g_lane = (n >> 2) * H_ + hbase + (n & 3);
  const int rowb = w * 16 + quad * 4;
  const bool low8  = (n & 8) == 0;          // lanes holding (i,j) pairs
  const bool first = (n & 4) == 0;          // first gate of the pair

  short8 bfr[32];
  {
    const unsigned short* bp = wh_t + (size_t)g_lane * H_ + quad * 8;
    #pragma unroll
    for (int kt = 0; kt < 32; ++kt)
      bfr[kt] = *reinterpret_cast<const short8*>(bp + kt * 32);
  }
  #pragma unroll
  for (int kt = 0; kt < 32; ++kt)
    __asm__ volatile("" : "+a"(bfr[kt]));   // park Wh in the AGPR file

  float creg[4] = {0.f, 0.f, 0.f, 0.f};
  ushort4 xgv = *reinterpret_cast<const ushort4*>(xgp + ((size_t)wg * 256 + tid) * 4);

  for (int t = 0; t < T_; ++t){
    // A-fragments: flat burst of 32 x 16B loads of h_t, pinned -> all in flight
    const unsigned short* asrc = hb + (size_t)t * HS_ + (size_t)(w * 16 + n) * H_ + quad * 8;
    short8 afr[32];
    #pragma unroll
    for (int kt = 0; kt < 32; ++kt)
      afr[kt] = *reinterpret_cast<const short8*>(asrc + kt * 32);
    #pragma unroll
    for (int kt = 0; kt < 32; ++kt)
      __asm__ volatile("" : "+v"(afr[kt]));

    floatx4 a0 = {0.f,0.f,0.f,0.f}, a1 = {0.f,0.f,0.f,0.f};
    floatx4 a2 = {0.f,0.f,0.f,0.f}, a3 = {0.f,0.f,0.f,0.f};
    #pragma unroll
    for (int kt = 0; kt < 32; kt += 4){
      a0 = __builtin_amdgcn_mfma_f32_16x16x32_bf16(afr[kt + 0], bfr[kt + 0], a0, 0, 0, 0);
      a1 = __builtin_amdgcn_mfma_f32_16x16x32_bf16(afr[kt + 1], bfr[kt + 1], a1, 0, 0, 0);
      a2 = __builtin_amdgcn_mfma_f32_16x16x32_bf16(afr[kt + 2], bfr[kt + 2], a2, 0, 0, 0);
      a3 = __builtin_amdgcn_mfma_f32_16x16x32_bf16(afr[kt + 3], bfr[kt + 3], a3, 0, 0, 0);
    }
    floatx4 acc = (a0 + a1) + (a2 + a3);
    acc[0] += bf2f(xgv.x); acc[1] += bf2f(xgv.y);
    acc[2] += bf2f(xgv.z); acc[3] += bf2f(xgv.w);

    // pointwise: lane col n -> gate n>>2, h-offset n&3.  Pair up via shuffles.
    float r1o[4], q1[4], q2[4];
    #pragma unroll
    for (int reg = 0; reg < 4; ++reg){
      const float a_ = acc[reg];
      const float p_ = __shfl_xor(a_, 4);   // swap i<->j and f<->o
      const float x1 = first ? a_ : p_;     // i (low) / f (high)
      const float x2 = first ? p_ : a_;     // j (low) / o (high)
      const float s1 = sigmoidf_(low8 ? x1 : (x1 + 1.0f));   // sig(i) or sig(f+1)
      const float r1 = low8 ? s1 * tanhf_(x2) : s1;          // sig(i)*tanh(j) or sig(f+1)
      const float r2 = low8 ? 0.0f : sigmoidf_(x2);          // sig(o)
      r1o[reg] = r1;
      q1[reg] = __shfl_xor(r1, 8);          // low lanes receive sig(f+1)
      q2[reg] = __shfl_xor(r2, 8);          // low lanes receive sig(o)
    }
    if (n < 4){
      unsigned short* hout = hb + (size_t)(t + 1) * HS_;
      #pragma unroll
      for (int reg = 0; reg < 4; ++reg){
        const float cn = creg[reg] * q1[reg] + r1o[reg];
        creg[reg] = cn;
        const float hv = tanhf_(cn) * q2[reg];
        __hip_atomic_store(&hout[(size_t)(rowb + reg) * H_ + hbase + n], f2bf(hv),
                           __ATOMIC_RELAXED, __HIP_MEMORY_SCOPE_AGENT);
        if (t == T_ - 1) hT[(size_t)(hbase + n) * B_ + rowb + reg] = hv;
      }
    }
    // Master/release grid barrier with pipelined polling (R6 change).
    if (t < T_ - 1){
      // prefetch next step's x-gates: its HBM RTT rides the store-ack drain
      // inside the same pre-barrier vmcnt(0) (R5 post-mortem: this is free)
      const ushort4 xgv_n = *reinterpret_cast<const ushort4*>(
          xgp + (((size_t)(t + 1) * 256 + wg) * 256 + tid) * 4);
      __syncthreads();                      // drains h stores (vmcnt 0)
      if (tid == 0){
        const unsigned step = (unsigned)(t + 1);
        __asm__ volatile("" ::: "memory");
        __hip_atomic_fetch_add(&bar[(wg & 15) * 32], 1u,
                               __ATOMIC_RELAXED, __HIP_MEMORY_SCOPE_AGENT);
        if (wg == 0){
          const unsigned tgt = step * 256u;
          for (;;){
            unsigned a[16], b[16];
            #pragma unroll
            for (int i = 0; i < 16; ++i)
              a[i] = __hip_atomic_load(&bar[i * 32],
                                       __ATOMIC_RELAXED, __HIP_MEMORY_SCOPE_AGENT);
            #pragma unroll
            for (int i = 0; i < 16; ++i)
              b[i] = __hip_atomic_load(&bar[i * 32],
                                       __ATOMIC_RELAXED, __HIP_MEMORY_SCOPE_AGENT);
            unsigned s = 0;
            #pragma unroll
            for (int i = 0; i < 16; ++i) s += a[i];
            if (s >= tgt) break;
            s = 0;
            #pragma unroll
            for (int i = 0; i < 16; ++i) s += b[i];
            if (s >= tgt) break;
          }
          #pragma unroll
          for (int i = 0; i < 16; ++i)
            __hip_atomic_store(&bar[512 + i * 32], step,
                               __ATOMIC_RELAXED, __HIP_MEMORY_SCOPE_AGENT);
        } else {
          unsigned int* rel = &bar[512 + (wg & 15) * 32];
          for (;;){
            const unsigned r0 = __hip_atomic_load(rel, __ATOMIC_RELAXED, __HIP_MEMORY_SCOPE_AGENT);
            const unsigned r1 = __hip_atomic_load(rel, __ATOMIC_RELAXED, __HIP_MEMORY_SCOPE_AGENT);
            const unsigned r2 = __hip_atomic_load(rel, __ATOMIC_RELAXED, __HIP_MEMORY_SCOPE_AGENT);
            const unsigned r3 = __hip_atomic_load(rel, __ATOMIC_RELAXED, __HIP_MEMORY_SCOPE_AGENT);
            if (r0 >= step) break;
            if (r1 >= step) break;
            if (r2 >= step) break;
            if (r3 >= step) break;
          }
        }
        __asm__ volatile("" ::: "memory");
      }
      __syncthreads();
      xgv = xgv_n;
    }
  }
}

// ---------------- projection: out = h127 @ w_out + b_out, single pass ----------------
// grid 500, block 256: each block 64 v-cols x 64 b-rows, full K=1024, bias fused.
__global__ __launch_bounds__(256) void k_proj(const float* __restrict__ w_out,
    const float* __restrict__ hT, const float* __restrict__ b_out,
    float* __restrict__ out){
  __shared__ float wsh[32 * 68];
  __shared__ float hsh[32 * 68];
  const int tid = threadIdx.x;
  const int vbase = blockIdx.x * 64;
  const int vq = tid & 15, bg = tid >> 4;
  floatx4 acc[4] = {{0,0,0,0},{0,0,0,0},{0,0,0,0},{0,0,0,0}};
  for (int c = 0; c < 32; ++c){
    const int k0 = c * 32;
    __syncthreads();
    #pragma unroll
    for (int i = 0; i < 2; ++i){
      const int flat = tid + i * 256;
      const int row = flat >> 4, c4 = (flat & 15) << 2;
      *reinterpret_cast<float4*>(&wsh[row * 68 + c4]) =
        *reinterpret_cast<const float4*>(w_out + (size_t)(k0 + row) * V_ + vbase + c4);
      *reinterpret_cast<float4*>(&hsh[row * 68 + c4]) =
        *reinterpret_cast<const float4*>(hT + (size_t)(k0 + row) * B_ + c4);
    }
    __syncthreads();
    #pragma unroll 8
    for (int k = 0; k < 32; ++k){
      const floatx4 wv = *reinterpret_cast<const floatx4*>(&wsh[k * 68 + vq * 4]);
      #pragma unroll
      for (int j = 0; j < 4; ++j){
        acc[j] += hsh[k * 68 + bg * 4 + j] * wv;
      }
    }
  }
  const floatx4 bv = *reinterpret_cast<const floatx4*>(b_out + vbase + vq * 4);
  #pragma unroll
  for (int j = 0; j < 4; ++j){
    *reinterpret_cast<floatx4*>(out + (size_t)(bg * 4 + j) * V_ + vbase + vq * 4) = acc[j] + bv;
  }
}

extern "C" void kernel_launch(void* const* d_in, const int* in_sizes, int n_in,
                              void* d_out, int out_size, void* d_ws, size_t ws_size,
                              hipStream_t stream){
  (void)in_sizes; (void)n_in; (void)out_size; (void)ws_size;
  const float* x     = (const float*)d_in[0];
  const float* kern  = (const float*)d_in[1];
  const float* bias  = (const float*)d_in[2];
  const float* w_out = (const float*)d_in[3];
  const float* b_out = (const float*)d_in[4];
  float* out = (float*)d_out;
  char* ws = (char*)d_ws;

  const size_t BAR_OFF = 0;                              // 4 KB barrier state:
                                                         //  [0,2048)  16 arrival lines (128B stride)
                                                         //  [2048,4096) 16 release lines (128B stride)
  const size_t HB_OFF  = 4096;                           // 129 h buffers, bf16 [64][1024]
  const size_t HT_OFF  = HB_OFF + (size_t)129 * 131072;  // h127 transposed fp32 [1024][64]
  const size_t WX_OFF  = HT_OFF + 262144;                // Wx^T bf16 [4096][256]
  const size_t WH_OFF  = WX_OFF + 2097152;               // Wh^T bf16 [4096][1024]
  const size_t XG_OFF  = WH_OFF + 8388608;               // xgates bf16 permuted (67 MB)

  unsigned int*   bar  = (unsigned int*)(ws + BAR_OFF);
  unsigned short* hb   = (unsigned short*)(ws + HB_OFF);
  float*          hT   = (float*)(ws + HT_OFF);
  unsigned short* wx_t = (unsigned short*)(ws + WX_OFF);
  unsigned short* wh_t = (unsigned short*)(ws + WH_OFF);
  unsigned short* xgp  = (unsigned short*)(ws + XG_OFF);

  hipMemsetAsync(ws, 0, HB_OFF + 131072, stream);  // zero barrier + h buffer 0
  k_transpose<<<dim3(40, 128), 256, 0, stream>>>(kern, wx_t, wh_t);
  k_xgates<<<dim3(128, 16), 256, 0, stream>>>(x, wx_t, bias, xgp);
  k_lstm<<<dim3(256), 256, 0, stream>>>(wh_t, xgp, hb, hT, bar);
  k_proj<<<dim3(500), 256, 0, stream>>>(w_out, hT, b_out, out);
}